// Round 13
// baseline (937.868 us; speedup 1.0000x reference)
//
#include <hip/hip_runtime.h>
#include <hip/hip_cooperative_groups.h>
#include <hip/hip_bf16.h>

namespace cg = cooperative_groups;

#define NODES 100000
#define EDGES 1600000
#define NBINS ((NODES + 127) >> 7)   // 782 bins, 128 nodes each
#define BINCAP 4096                  // LDS entries per bin (mean 2046)
#define GMAX 1024                    // max grid (4 blocks/CU x 256 CU)
#define NTILES ((NODES + 63) / 64)   // 1563 row-tiles
#define NQUADS ((NODES + 3) / 4)     // 25000 gather units (4 nodes each)
#define SMEM_BYTES 35840             // 64*136*2 (S) + 128*72*2 (Wbuf) -> 4 blocks/CU

typedef __bf16 bf16x8 __attribute__((ext_vector_type(8)));
typedef float f32x4 __attribute__((ext_vector_type(4)));

__device__ __forceinline__ unsigned short f2b(float f) {
  __hip_bfloat16 h = __float2bfloat16(f);   // RNE
  return __builtin_bit_cast(unsigned short, h);
}
__device__ __forceinline__ float b_lo(unsigned u) { return __uint_as_float(u << 16); }
__device__ __forceinline__ float b_hi(unsigned u) { return __uint_as_float(u & 0xffff0000u); }

struct MegaParams {
  const float4* x4;
  const int* src;
  const int* dst;
  const float* W1; const float* b1; const float* W2; const float* b2;
  const float* W3; const float* b3; const float* W4; const float* b4;
  unsigned short* xh; unsigned short* hA; unsigned short* hB;
  unsigned short* Wt1; unsigned short* Wt2; unsigned short* Wt3; unsigned short* Wt4;
  int* rowstart; int* binStart; int* binTotal; int* partialT; int* blockoffT;
  unsigned* coarse; int* bucket;
  float* out;
};

// ---------------------------------------------------------------------------
// gather: out[n,:] = x[n,:] + sum_nbr x  (one node per wave, 4 loads deep)
// Identical numerics to R10-R12 standalone gather.
// ---------------------------------------------------------------------------
__device__ __forceinline__ void gather_quad(
    const uint4* __restrict__ xq, const int* __restrict__ rowstart,
    const int* __restrict__ bucket, uint4* __restrict__ outq, int u, int tid) {
  const int n = u * 4 + (tid >> 6);
  if (n >= NODES) return;
  const int lane = tid & 63;
  const int g = lane >> 4;
  const int fl = lane & 15;

  float a[8] = {0.f, 0.f, 0.f, 0.f, 0.f, 0.f, 0.f, 0.f};
  if (g == 0) {
    uint4 v = xq[(size_t)n * 16 + fl];
    a[0] = b_lo(v.x); a[1] = b_hi(v.x);
    a[2] = b_lo(v.y); a[3] = b_hi(v.y);
    a[4] = b_lo(v.z); a[5] = b_hi(v.z);
    a[6] = b_lo(v.w); a[7] = b_hi(v.w);
  }
  const int beg = rowstart[n];
  const int end = rowstart[n + 1];
  for (int j = beg; j < end; j += 16) {
    int e0 = j + g, e1 = j + 4 + g, e2 = j + 8 + g, e3 = j + 12 + g;
    int i0 = (e0 < end) ? e0 : (end - 1);
    int i1 = (e1 < end) ? e1 : (end - 1);
    int i2 = (e2 < end) ? e2 : (end - 1);
    int i3 = (e3 < end) ? e3 : (end - 1);
    int s0 = bucket[i0], s1 = bucket[i1], s2 = bucket[i2], s3 = bucket[i3];
    uint4 v0 = xq[(size_t)s0 * 16 + fl];
    uint4 v1 = xq[(size_t)s1 * 16 + fl];
    uint4 v2 = xq[(size_t)s2 * 16 + fl];
    uint4 v3 = xq[(size_t)s3 * 16 + fl];
    float m0 = (e0 < end) ? 1.f : 0.f;
    float m1 = (e1 < end) ? 1.f : 0.f;
    float m2 = (e2 < end) ? 1.f : 0.f;
    float m3 = (e3 < end) ? 1.f : 0.f;
    a[0] = fmaf(b_lo(v0.x), m0, a[0]); a[1] = fmaf(b_hi(v0.x), m0, a[1]);
    a[2] = fmaf(b_lo(v0.y), m0, a[2]); a[3] = fmaf(b_hi(v0.y), m0, a[3]);
    a[4] = fmaf(b_lo(v0.z), m0, a[4]); a[5] = fmaf(b_hi(v0.z), m0, a[5]);
    a[6] = fmaf(b_lo(v0.w), m0, a[6]); a[7] = fmaf(b_hi(v0.w), m0, a[7]);
    a[0] = fmaf(b_lo(v1.x), m1, a[0]); a[1] = fmaf(b_hi(v1.x), m1, a[1]);
    a[2] = fmaf(b_lo(v1.y), m1, a[2]); a[3] = fmaf(b_hi(v1.y), m1, a[3]);
    a[4] = fmaf(b_lo(v1.z), m1, a[4]); a[5] = fmaf(b_hi(v1.z), m1, a[5]);
    a[6] = fmaf(b_lo(v1.w), m1, a[6]); a[7] = fmaf(b_hi(v1.w), m1, a[7]);
    a[0] = fmaf(b_lo(v2.x), m2, a[0]); a[1] = fmaf(b_hi(v2.x), m2, a[1]);
    a[2] = fmaf(b_lo(v2.y), m2, a[2]); a[3] = fmaf(b_hi(v2.y), m2, a[3]);
    a[4] = fmaf(b_lo(v2.z), m2, a[4]); a[5] = fmaf(b_hi(v2.z), m2, a[5]);
    a[6] = fmaf(b_lo(v2.w), m2, a[6]); a[7] = fmaf(b_hi(v2.w), m2, a[7]);
    a[0] = fmaf(b_lo(v3.x), m3, a[0]); a[1] = fmaf(b_hi(v3.x), m3, a[1]);
    a[2] = fmaf(b_lo(v3.y), m3, a[2]); a[3] = fmaf(b_hi(v3.y), m3, a[3]);
    a[4] = fmaf(b_lo(v3.z), m3, a[4]); a[5] = fmaf(b_hi(v3.z), m3, a[5]);
    a[6] = fmaf(b_lo(v3.w), m3, a[6]); a[7] = fmaf(b_hi(v3.w), m3, a[7]);
  }
#pragma unroll
  for (int k = 0; k < 8; k++) {
    a[k] += __shfl_xor(a[k], 16, 64);
    a[k] += __shfl_xor(a[k], 32, 64);
  }
  if (lane < 16) {
    uint4 o;
    o.x = ((unsigned)f2b(a[1]) << 16) | f2b(a[0]);
    o.y = ((unsigned)f2b(a[3]) << 16) | f2b(a[2]);
    o.z = ((unsigned)f2b(a[5]) << 16) | f2b(a[4]);
    o.w = ((unsigned)f2b(a[7]) << 16) | f2b(a[6]);
    outq[(size_t)n * 16 + fl] = o;
  }
}

// ---------------------------------------------------------------------------
// mlp tile: out[64 rows] = relu( relu(A @ Wa^T + ba) @ Wb^T + bb )
// 64-wide weight slices in LDS (stride 72 shorts -> 2-way bank = free).
// All S-row accesses wave-private; barriers only around Wbuf reuse.
// ---------------------------------------------------------------------------
template <int K, int N1, int N2, bool OUT_F32>
__device__ __forceinline__ void mlp_tile(
    const unsigned short* __restrict__ A,
    const unsigned short* __restrict__ Wa, const float* __restrict__ ba,
    const unsigned short* __restrict__ Wb, const float* __restrict__ bb,
    void* __restrict__ Cout, int tile, int tid, char* smem) {
  constexpr int LDA = K + 8;
  constexpr int LWS = 72;              // slice row stride (shorts)
  constexpr int NT1 = N1 / 16, NT2 = N2 / 16;
  constexpr int NSL1 = K / 64, NSL2 = N1 / 64;
  unsigned short* S = (unsigned short*)smem;       // 64*LDA
  unsigned short* Wbuf = S + 64 * LDA;             // max(N1,N2)*LWS

  const int wave = tid >> 6, lane = tid & 63, g = lane >> 4, fl = lane & 15;
  const int rowBase = tile * 64;
  const int arow = wave * 16 + fl;

  // stage A tile
  for (int i = tid; i < 64 * (K / 8); i += 256) {
    int r = i / (K / 8), c = i % (K / 8);
    uint4 v = make_uint4(0, 0, 0, 0);
    if (rowBase + r < NODES)
      v = ((const uint4*)A)[(size_t)(rowBase + r) * (K / 8) + c];
    *(uint4*)&S[r * LDA + c * 8] = v;
  }

  // GEMM1 over 64-wide slices of Wa
  f32x4 acc[NT1];
#pragma unroll
  for (int c = 0; c < NT1; c++) acc[c] = (f32x4){0.f, 0.f, 0.f, 0.f};
#pragma unroll
  for (int s = 0; s < NSL1; s++) {
    for (int i = tid; i < N1 * 8; i += 256) {
      int n = i >> 3, c = i & 7;
      *(uint4*)&Wbuf[n * LWS + c * 8] = *(const uint4*)&Wa[(size_t)n * K + s * 64 + c * 8];
    }
    __syncthreads();   // covers A-stage (first slice) + Wbuf stores
#pragma unroll
    for (int kbl = 0; kbl < 2; kbl++) {
      bf16x8 av = *(const bf16x8*)&S[arow * LDA + (s * 2 + kbl) * 32 + g * 8];
#pragma unroll
      for (int c = 0; c < NT1; c++) {
        bf16x8 bv = *(const bf16x8*)&Wbuf[(c * 16 + fl) * LWS + kbl * 32 + g * 8];
        acc[c] = __builtin_amdgcn_mfma_f32_16x16x32_bf16(av, bv, acc[c], 0, 0, 0);
      }
    }
    __syncthreads();   // all reads done before Wbuf overwrite
  }
  // t1 writeback into wave-private rows of S
#pragma unroll
  for (int c = 0; c < NT1; c++) {
    int col = c * 16 + fl;
    float bv = ba[col];
#pragma unroll
    for (int reg = 0; reg < 4; reg++) {
      int rloc = wave * 16 + g * 4 + reg;
      S[rloc * LDA + col] = f2b(fmaxf(acc[c][reg] + bv, 0.f));
    }
  }
  // GEMM2 over 64-wide slices of Wb
  f32x4 acc2[NT2];
#pragma unroll
  for (int c = 0; c < NT2; c++) acc2[c] = (f32x4){0.f, 0.f, 0.f, 0.f};
#pragma unroll
  for (int s = 0; s < NSL2; s++) {
    for (int i = tid; i < N2 * 8; i += 256) {
      int n = i >> 3, c = i & 7;
      *(uint4*)&Wbuf[n * LWS + c * 8] = *(const uint4*)&Wb[(size_t)n * N1 + s * 64 + c * 8];
    }
    __syncthreads();
#pragma unroll
    for (int kbl = 0; kbl < 2; kbl++) {
      bf16x8 av = *(const bf16x8*)&S[arow * LDA + (s * 2 + kbl) * 32 + g * 8];
#pragma unroll
      for (int c = 0; c < NT2; c++) {
        bf16x8 bv = *(const bf16x8*)&Wbuf[(c * 16 + fl) * LWS + kbl * 32 + g * 8];
        acc2[c] = __builtin_amdgcn_mfma_f32_16x16x32_bf16(av, bv, acc2[c], 0, 0, 0);
      }
    }
    __syncthreads();   // protects S + Wbuf before next tile iteration
  }
#pragma unroll
  for (int c = 0; c < NT2; c++) {
    int col = c * 16 + fl;
    float bv = bb[col];
#pragma unroll
    for (int reg = 0; reg < 4; reg++) {
      int row = rowBase + wave * 16 + g * 4 + reg;
      if (row < NODES) {
        float v = fmaxf(acc2[c][reg] + bv, 0.f);
        if (OUT_F32)
          ((float*)Cout)[(size_t)row * N2 + col] = v;
        else
          ((unsigned short*)Cout)[(size_t)row * N2 + col] = f2b(v);
      }
    }
  }
}

// ---------------------------------------------------------------------------
// The mega-kernel: all 9 former dispatches, grid.sync between phases.
// ---------------------------------------------------------------------------
__global__ __launch_bounds__(256, 4) void gin_mega(MegaParams p) {
  __shared__ __align__(16) char smem[SMEM_BYTES];
  cg::grid_group gg = cg::this_grid();
  const int tid = threadIdx.x;
  const int bid = blockIdx.x;
  const int gd = gridDim.x;

  // ---- phase 0: cast x, transpose+cast weights, coarse-bin histogram ----
  {
    const size_t stride = (size_t)gd * 256;
    for (size_t i = (size_t)bid * 256 + tid; i < (size_t)NODES * 32; i += stride) {
      float4 v = p.x4[i];
      ushort4 o;
      o.x = f2b(v.x); o.y = f2b(v.y); o.z = f2b(v.z); o.w = f2b(v.w);
      ((ushort4*)p.xh)[i] = o;
    }
    for (int i = bid * 256 + tid; i < 45056; i += gd * 256) {
      if (i < 16384) { int n = i >> 7, k = i & 127; p.Wt1[i] = f2b(p.W1[k * 128 + n]); }
      else if (i < 32768) { int j = i - 16384; int n = j >> 7, k = j & 127; p.Wt2[j] = f2b(p.W2[k * 128 + n]); }
      else if (i < 40960) { int j = i - 32768; int n = j >> 7, k = j & 127; p.Wt3[j] = f2b(p.W3[k * 64 + n]); }
      else { int j = i - 40960; int n = j >> 6, k = j & 63; p.Wt4[j] = f2b(p.W4[k * 64 + n]); }
    }
    int* h = (int*)smem;
    for (int i = tid; i < NBINS; i += 256) h[i] = 0;
    __syncthreads();
    const int chunk = (EDGES + gd - 1) / gd;
    const int beg = bid * chunk, end = min(beg + chunk, EDGES);
    for (int e = beg + tid; e < end; e += 256) atomicAdd(&h[p.dst[e] >> 7], 1);
    __syncthreads();
    for (int i = tid; i < NBINS; i += 256) p.partialT[(size_t)i * GMAX + bid] = h[i];
  }
  gg.sync();

  // ---- phase 1: per-bin exclusive scan across gd producer blocks ----
  for (int bin = bid; bin < NBINS; bin += gd) {
    int* s = (int*)smem;
    const size_t base = (size_t)bin * GMAX;
    int v[4]; int sum = 0;
#pragma unroll
    for (int k = 0; k < 4; k++) {
      int idx = tid * 4 + k;
      v[k] = (idx < gd) ? p.partialT[base + idx] : 0;
      sum += v[k];
    }
    s[tid] = sum;
    __syncthreads();
    for (int off = 1; off < 256; off <<= 1) {
      int u = (tid >= off) ? s[tid - off] : 0;
      __syncthreads();
      s[tid] += u;
      __syncthreads();
    }
    int run = s[tid] - sum;
#pragma unroll
    for (int k = 0; k < 4; k++) {
      int idx = tid * 4 + k;
      if (idx < gd) p.blockoffT[base + idx] = run;
      run += v[k];
    }
    if (tid == 255) p.binTotal[bin] = s[255];
    __syncthreads();
  }
  gg.sync();

  // ---- phase 2: scan 782 bin totals -> binStart (block 0) ----
  if (bid == 0) {
    int* s = (int*)smem;
    int v[4]; int sum = 0;
#pragma unroll
    for (int k = 0; k < 4; k++) {
      int idx = tid * 4 + k;
      v[k] = (idx < NBINS) ? p.binTotal[idx] : 0;
      sum += v[k];
    }
    s[tid] = sum;
    __syncthreads();
    for (int off = 1; off < 256; off <<= 1) {
      int u = (tid >= off) ? s[tid - off] : 0;
      __syncthreads();
      s[tid] += u;
      __syncthreads();
    }
    int run = s[tid] - sum;
#pragma unroll
    for (int k = 0; k < 4; k++) {
      int idx = tid * 4 + k;
      if (idx < NBINS) p.binStart[idx] = run;
      run += v[k];
    }
    if (tid == 0) { p.binStart[NBINS] = EDGES; p.rowstart[NODES] = EDGES; }
  }
  gg.sync();

  // ---- phase 3: scatter edges into coarse bins ----
  {
    int* base = (int*)smem;
    int* h = base + NBINS;
    for (int i = tid; i < NBINS; i += 256) {
      base[i] = p.binStart[i] + p.blockoffT[(size_t)i * GMAX + bid];
      h[i] = 0;
    }
    __syncthreads();
    const int chunk = (EDGES + gd - 1) / gd;
    const int beg = bid * chunk, end = min(beg + chunk, EDGES);
    for (int e = beg + tid; e < end; e += 256) {
      int d = p.dst[e];
      int b = d >> 7;
      int pos = base[b] + atomicAdd(&h[b], 1);
      p.coarse[pos] = (unsigned)p.src[e] | ((unsigned)(d & 127) << 17);
    }
  }
  gg.sync();

  // ---- phase 4: per-bin LDS counting sort -> rowstart + bucket ----
  for (int b = bid; b < NBINS; b += gd) {
    unsigned* ent = (unsigned*)smem;
    unsigned* obuf = ent + BINCAP;
    int* deg = (int*)(obuf + BINCAP);
    int* pre = deg + 128;
    const int s0 = p.binStart[b];
    const int nE = p.binStart[b + 1] - s0;
    const int binBase = b << 7;
    if (tid < 128) deg[tid] = 0;
    __syncthreads();
    for (int i = tid; i < nE; i += 256) {
      unsigned e = p.coarse[s0 + i];
      ent[i] = e;
      atomicAdd(&deg[e >> 17], 1);
    }
    __syncthreads();
    int v = 0;
    if (tid < 128) { v = deg[tid]; pre[tid] = v; }
    __syncthreads();
    for (int off = 1; off < 128; off <<= 1) {
      int u = (tid >= off && tid < 128) ? pre[tid - off] : 0;
      __syncthreads();
      if (tid < 128) pre[tid] += u;
      __syncthreads();
    }
    if (tid < 128) {
      int ex = pre[tid] - v;
      if (binBase + tid < NODES) p.rowstart[binBase + tid] = s0 + ex;
      deg[tid] = ex;
    }
    __syncthreads();
    for (int i = tid; i < nE; i += 256) {
      unsigned e = ent[i];
      int pos = atomicAdd(&deg[e >> 17], 1);
      obuf[pos] = e & 0x1FFFFu;
    }
    __syncthreads();
    for (int i = tid; i < nE; i += 256) p.bucket[s0 + i] = (int)obuf[i];
    __syncthreads();
  }
  gg.sync();

  // ---- phase 5: gather 1 (xh -> hA) ----
  for (int u = bid; u < NQUADS; u += gd)
    gather_quad((const uint4*)p.xh, p.rowstart, p.bucket, (uint4*)p.hA, u, tid);
  gg.sync();

  // ---- phase 6: MLP 1 (hA -> hB) ----
  for (int t = bid; t < NTILES; t += gd)
    mlp_tile<128, 128, 128, false>(p.hA, p.Wt1, p.b1, p.Wt2, p.b2, p.hB, t, tid, smem);
  gg.sync();

  // ---- phase 7: gather 2 (hB -> hA) ----
  for (int u = bid; u < NQUADS; u += gd)
    gather_quad((const uint4*)p.hB, p.rowstart, p.bucket, (uint4*)p.hA, u, tid);
  gg.sync();

  // ---- phase 8: MLP 2 (hA -> out, f32) ----
  for (int t = bid; t < NTILES; t += gd)
    mlp_tile<128, 64, 64, true>(p.hA, p.Wt3, p.b3, p.Wt4, p.b4, p.out, t, tid, smem);
}

// ---------------------------------------------------------------------------
// launch
// ---------------------------------------------------------------------------
extern "C" void kernel_launch(void* const* d_in, const int* in_sizes, int n_in,
                              void* d_out, int out_size, void* d_ws, size_t ws_size,
                              hipStream_t stream) {
  MegaParams p;
  p.x4 = (const float4*)d_in[0];
  const int* ei = (const int*)d_in[1];
  p.src = ei;                 // edge_index[0]
  p.dst = ei + EDGES;         // edge_index[1]
  p.W1 = (const float*)d_in[2];  p.b1 = (const float*)d_in[3];
  p.W2 = (const float*)d_in[4];  p.b2 = (const float*)d_in[5];
  p.W3 = (const float*)d_in[6];  p.b3 = (const float*)d_in[7];
  p.W4 = (const float*)d_in[8];  p.b4 = (const float*)d_in[9];
  p.out = (float*)d_out;

  char* ws = (char*)d_ws;
  p.xh = (unsigned short*)ws;                               // 25.6 MB
  p.hA = p.xh + (size_t)NODES * 128;                        // 25.6 MB
  p.hB = p.hA + (size_t)NODES * 128;                        // 25.6 MB
  p.Wt1 = p.hB + (size_t)NODES * 128;                       // 128*128
  p.Wt2 = p.Wt1 + 128 * 128;
  p.Wt3 = p.Wt2 + 128 * 128;                                // 64*128
  p.Wt4 = p.Wt3 + 64 * 128;                                 // 64*64
  p.rowstart = (int*)(p.Wt4 + 64 * 64);                     // NODES+1
  p.binStart = p.rowstart + NODES + 1;                      // NBINS+1
  p.binTotal = p.binStart + NBINS + 1;                      // NBINS
  p.partialT = p.binTotal + NBINS;                          // NBINS*GMAX (3.2 MB)
  p.blockoffT = p.partialT + (size_t)NBINS * GMAX;          // NBINS*GMAX (3.2 MB)
  p.coarse = (unsigned*)(p.blockoffT + (size_t)NBINS * GMAX); // EDGES (6.4 MB)
  p.bucket = (int*)(p.coarse + EDGES);                      // EDGES (6.4 MB)

  int maxb = 0;
  hipOccupancyMaxActiveBlocksPerMultiprocessor(&maxb, gin_mega, 256, 0);
  int grid = maxb * 256;        // 256 CUs
  if (grid > GMAX) grid = GMAX;
  if (grid < 256) grid = 256;   // paranoia floor (all phases grid-stride safe)

  void* args[] = {(void*)&p};
  hipLaunchCooperativeKernel(gin_mega, dim3(grid), dim3(256), args, 0, stream);
}